// Round 1
// baseline (150.920 us; speedup 1.0000x reference)
//
#include <hip/hip_runtime.h>
#include <cstdint>

// ---------------------------------------------------------------------------
// MoDBlock: B=2, T=2048, C=512, E=2, NH=8, hs=64, k=1024 (hardcoded; harness
// always uses setup_inputs()). Output: out [B,T,C] f32 (2097152) + loss (1).
// ---------------------------------------------------------------------------

#define DI __device__ __forceinline__

typedef __bf16 bf16x8 __attribute__((ext_vector_type(8)));
typedef float  f32x4  __attribute__((ext_vector_type(4)));

DI uint16_t f2bf(float f) {
    union { float f; uint32_t u; } v; v.f = f;
    uint32_t u = v.u;
    uint32_t r = (u + 0x7FFFu + ((u >> 16) & 1u)) >> 16;   // RNE; finite inputs only
    return (uint16_t)r;
}

DI f32x4 mfma16(bf16x8 a, bf16x8 b, f32x4 c) {
    return __builtin_amdgcn_mfma_f32_16x16x32_bf16(a, b, c, 0, 0, 0);
}

// ---- workspace layout (bytes) ----
constexpr size_t OFF_LOGITS = 0;                               // 4096 f32
constexpr size_t OFF_MASK   = OFF_LOGITS + 4096 * 4;           // 4096 int
constexpr size_t OFF_IDX    = OFF_MASK   + 4096 * 4;           // 2048 int
constexpr size_t OFF_WSEL   = OFF_IDX    + 2048 * 4;           // 2048 f32
constexpr size_t OFF_GATE   = OFF_WSEL   + 2048 * 4;           // 2048*2 f32
constexpr size_t OFF_LOSSP  = OFF_GATE   + 4096 * 4;           // 1024 f32
constexpr size_t OFF_SELBF  = OFF_LOSSP  + 1024 * 4;           // 2048*512 bf16
constexpr size_t OFF_WQKVT  = OFF_SELBF  + 2048 * 512 * 2;     // 2048*512 bf16 (W^T)
constexpr size_t OFF_WPROJT = OFF_WQKVT  + 2048 * 512 * 2;     // 512*512 bf16 (W^T)
constexpr size_t OFF_QKVRAW = OFF_WPROJT + 512 * 512 * 2;      // 2048*2048 f32
constexpr size_t OFF_QH     = OFF_QKVRAW + (size_t)2048 * 2048 * 4; // [B,E,NH,k,64] bf16
constexpr size_t OFF_KH     = OFF_QH     + (size_t)2097152 * 2;     // [B,NH,k,64] bf16
constexpr size_t OFF_VT     = OFF_KH     + (size_t)1048576 * 2;     // [B,NH,64,k] bf16
constexpr size_t OFF_YBF    = OFF_VT     + (size_t)1048576 * 2;     // [B,E,k,512] bf16
constexpr size_t OFF_YPROJ  = OFF_YBF    + (size_t)4096 * 512 * 2;  // [B,E,k,512] f32

// ---------------------------------------------------------------------------
// 1. router logits, f64 accumulation (top-k boundary safety). wave per row.
__global__ void k_logits(const float* __restrict__ x, const float* __restrict__ wr,
                         float* __restrict__ logits) {
    int wid  = (blockIdx.x * blockDim.x + threadIdx.x) >> 6;
    int lane = threadIdx.x & 63;
    if (wid >= 4096) return;
    const float* xr = x + (size_t)wid * 512;
    double s = 0.0;
#pragma unroll
    for (int j = 0; j < 8; j++) { int c = lane + 64 * j; s += (double)xr[c] * (double)wr[c]; }
    for (int m = 1; m < 64; m <<= 1) s += __shfl_xor(s, m);
    if (lane == 0) logits[wid] = (float)s;
}

// 2. rank: count of strictly-greater (or equal with smaller index) -> mask
__global__ void k_rank(const float* __restrict__ logits, int* __restrict__ mask) {
    int wid  = (blockIdx.x * blockDim.x + threadIdx.x) >> 6;
    int lane = threadIdx.x & 63;
    if (wid >= 4096) return;
    int b = wid >> 11, t = wid & 2047;
    const float* lb = logits + b * 2048;
    float v = lb[t];
    int cnt = 0;
    for (int j = 0; j < 32; j++) {
        int tp = lane + 64 * j;
        float lv = lb[tp];
        bool pred = (lv > v) || (lv == v && tp < t);
        cnt += __popcll(__ballot(pred));
    }
    if (lane == 0) mask[wid] = (cnt < 1024) ? 1 : 0;
}

// 3. prefix-scan of mask -> temporal-order idx + sigmoid weights. 1 block/batch.
__global__ void k_select(const float* __restrict__ logits, const int* __restrict__ mask,
                         int* __restrict__ idx, float* __restrict__ wsel) {
    __shared__ int s0[2048], s1[2048];
    int b = blockIdx.x, tid = threadIdx.x;
    int m0 = mask[b * 2048 + tid], m1 = mask[b * 2048 + tid + 1024];
    s0[tid] = m0; s0[tid + 1024] = m1;
    __syncthreads();
    int* src = s0; int* dst = s1;
    for (int off = 1; off < 2048; off <<= 1) {
        for (int q = 0; q < 2; q++) {
            int i = tid + q * 1024;
            int v = src[i];
            if (i >= off) v += src[i - off];
            dst[i] = v;
        }
        __syncthreads();
        int* tpp = src; src = dst; dst = tpp;
    }
    for (int q = 0; q < 2; q++) {
        int t = tid + q * 1024;
        int mk = (q == 0 ? m0 : m1);
        if (mk) {
            int pos = src[t] - 1;
            idx[b * 1024 + pos] = t;
            float v = logits[b * 2048 + t];
            wsel[b * 1024 + pos] = 1.f / (1.f + __expf(-v));
        }
    }
}

// 4. cast+transpose weights to bf16 [N][K]
__global__ void k_castw(const float* __restrict__ Wq, const float* __restrict__ Wkv,
                        const float* __restrict__ Wp,
                        uint16_t* __restrict__ Wqkvt, uint16_t* __restrict__ Wprojt) {
    int i = blockIdx.x * blockDim.x + threadIdx.x;
    const int total1 = 2048 * 512;
    if (i < total1) {
        int n = i >> 9, c = i & 511;
        float v = (n < 1024) ? Wq[c * 1024 + n] : Wkv[c * 1024 + (n - 1024)];
        Wqkvt[i] = f2bf(v);
    } else {
        int j = i - total1;
        if (j < 512 * 512) {
            int n = j >> 9, c = j & 511;
            Wprojt[j] = f2bf(Wp[c * 512 + n]);
        }
    }
}

// 5. gather selected rows -> bf16, and gate = softmax(sel @ W_gate) in f32
__global__ void k_gather_gate(const float* __restrict__ x, const int* __restrict__ idx,
                              const float* __restrict__ Wg,
                              uint16_t* __restrict__ selbf, float* __restrict__ gate) {
    __shared__ float red0[4], red1[4];
    int blk = blockIdx.x; int b = blk >> 10;
    int tid = threadIdx.x, lane = tid & 63, w = tid >> 6;
    int t = idx[blk];
    const float* xr = x + ((size_t)b * 2048 + t) * 512;
    int c = tid * 2;
    float v0 = xr[c], v1 = xr[c + 1];
    uint32_t pk = (uint32_t)f2bf(v0) | ((uint32_t)f2bf(v1) << 16);
    ((uint32_t*)(selbf + (size_t)blk * 512))[tid] = pk;
    float g0 = v0 * Wg[c * 2]     + v1 * Wg[(c + 1) * 2];
    float g1 = v0 * Wg[c * 2 + 1] + v1 * Wg[(c + 1) * 2 + 1];
    for (int m = 1; m < 64; m <<= 1) { g0 += __shfl_xor(g0, m); g1 += __shfl_xor(g1, m); }
    if (lane == 0) { red0[w] = g0; red1[w] = g1; }
    __syncthreads();
    if (tid == 0) {
        float a = red0[0] + red0[1] + red0[2] + red0[3];
        float bq = red1[0] + red1[1] + red1[2] + red1[3];
        float mx = fmaxf(a, bq);
        float ea = __expf(a - mx), eb = __expf(bq - mx), s = ea + eb;
        gate[blk * 2] = ea / s; gate[blk * 2 + 1] = eb / s;
    }
}

// 6. bf16 MFMA GEMM: C[M,N] f32 = A[M,K]bf16 @ Bt[N,K]bf16^T. 128x128 tile, BK=32.
__global__ __launch_bounds__(256) void k_gemm(const uint16_t* __restrict__ A,
                                              const uint16_t* __restrict__ Bt,
                                              float* __restrict__ Cc,
                                              int M, int N, int Kd) {
    __shared__ uint16_t As[128 * 40], Bs[128 * 40];   // pitch 40 -> 2-way max conflicts
    int tid = threadIdx.x, lane = tid & 63, w = tid >> 6;
    int m0 = blockIdx.x * 128, n0 = blockIdx.y * 128;
    int wr = (w >> 1) * 64, wc = (w & 1) * 64;
    f32x4 acc[4][4];
#pragma unroll
    for (int mt = 0; mt < 4; mt++)
#pragma unroll
        for (int nt = 0; nt < 4; nt++)
#pragma unroll
            for (int r = 0; r < 4; r++) acc[mt][nt][r] = 0.f;
    int arow = tid >> 2, akg = tid & 3;
    int K8 = Kd >> 3;
    const bf16x8* A8 = (const bf16x8*)A;
    const bf16x8* B8 = (const bf16x8*)Bt;
    for (int ks = 0; ks < Kd; ks += 32) {
        __syncthreads();
        int kc = (ks >> 3) + akg;
        bf16x8 va0 = A8[(size_t)(m0 + arow) * K8 + kc];
        bf16x8 va1 = A8[(size_t)(m0 + arow + 64) * K8 + kc];
        bf16x8 vb0 = B8[(size_t)(n0 + arow) * K8 + kc];
        bf16x8 vb1 = B8[(size_t)(n0 + arow + 64) * K8 + kc];
        *(bf16x8*)&As[arow * 40 + akg * 8] = va0;
        *(bf16x8*)&As[(arow + 64) * 40 + akg * 8] = va1;
        *(bf16x8*)&Bs[arow * 40 + akg * 8] = vb0;
        *(bf16x8*)&Bs[(arow + 64) * 40 + akg * 8] = vb1;
        __syncthreads();
        bf16x8 af[4], bfr[4];
#pragma unroll
        for (int t = 0; t < 4; t++) {
            af[t]  = *(const bf16x8*)&As[(wr + t * 16 + (lane & 15)) * 40 + (lane >> 4) * 8];
            bfr[t] = *(const bf16x8*)&Bs[(wc + t * 16 + (lane & 15)) * 40 + (lane >> 4) * 8];
        }
#pragma unroll
        for (int mt = 0; mt < 4; mt++)
#pragma unroll
            for (int nt = 0; nt < 4; nt++)
                acc[mt][nt] = mfma16(af[mt], bfr[nt], acc[mt][nt]);
    }
    int r0 = (lane >> 4) * 4, cl = lane & 15;
#pragma unroll
    for (int mt = 0; mt < 4; mt++)
#pragma unroll
        for (int nt = 0; nt < 4; nt++)
#pragma unroll
            for (int r = 0; r < 4; r++) {
                int row = m0 + wr + mt * 16 + r0 + r;
                int col = n0 + wc + nt * 16 + cl;
                Cc[(size_t)row * N + col] = acc[mt][nt][r];
            }
}

// 7. RMSNorm + RoPE -> head-layout bf16 Q,K and transposed V
__global__ void k_norm_rope(const float* __restrict__ qkv, const float* __restrict__ lnw,
                            uint16_t* __restrict__ Qh, uint16_t* __restrict__ Kh,
                            uint16_t* __restrict__ Vt) {
    __shared__ float red[4];
    int blk = blockIdx.x; int b = blk >> 10, i = blk & 1023;
    int tid = threadIdx.x, lane = tid & 63, w = tid >> 6;
    const float* row = qkv + (size_t)blk * 2048;
    int c0 = tid * 2;
    int d0 = c0 & 63, head = c0 >> 6;
    int j0 = d0 & 31, j1 = (d0 + 1) & 31;
    const float LN1E4_64 = 0.14391156831212787f;   // ln(10000)/64
    float fi = (float)i;
    float ang0 = fi * __expf(-(float)(4 * j0 + 1) * LN1E4_64);
    float ang1 = fi * __expf(-(float)(4 * j1 + 1) * LN1E4_64);
    float c_0 = cosf(ang0), s_0 = sinf(ang0);
    float c_1 = cosf(ang1), s_1 = sinf(ang1);
    float g0 = lnw[c0], g1 = lnw[c0 + 1];
    for (int which = 0; which < 3; which++) {        // q(e=0), q(e=1), k
        int off = which * 512;
        float u0 = row[off + c0], u1 = row[off + c0 + 1];
        float ss = u0 * u0 + u1 * u1;
        for (int m = 1; m < 64; m <<= 1) ss += __shfl_xor(ss, m);
        __syncthreads();
        if (lane == 0) red[w] = ss;
        __syncthreads();
        float tot = red[0] + red[1] + red[2] + red[3];
        float rinv = rsqrtf(tot * (1.0f / 512.0f) + 1e-6f);
        float n0 = u0 * rinv * g0, n1 = u1 * rinv * g1;
        float r0 = n0 * c_0 - n1 * s_0;              // even dim
        float r1 = n1 * c_1 + n0 * s_1;              // odd dim (different angle!)
        uint32_t pk = (uint32_t)f2bf(r0) | ((uint32_t)f2bf(r1) << 16);
        if (which < 2) {
            uint16_t* dst = Qh + ((size_t)((b * 2 + which) * 8 + head) * 1024 + i) * 64 + d0;
            *(uint32_t*)dst = pk;
        } else {
            uint16_t* dst = Kh + ((size_t)(b * 8 + head) * 1024 + i) * 64 + d0;
            *(uint32_t*)dst = pk;
        }
    }
    {   // v: no norm, no rope; store transposed [d][k]
        float u0 = row[1536 + c0], u1 = row[1536 + c0 + 1];
        Vt[((size_t)(b * 8 + head) * 64 + d0) * 1024 + i]     = f2bf(u0);
        Vt[((size_t)(b * 8 + head) * 64 + d0 + 1) * 1024 + i] = f2bf(u1);
    }
}

// 8. causal flash attention, bf16 MFMA. block = (b,e,h,q-tile of 64), wave = 16 q rows.
__global__ __launch_bounds__(256) void k_attn(const uint16_t* __restrict__ Qh,
                                              const uint16_t* __restrict__ Kh,
                                              const uint16_t* __restrict__ Vt,
                                              uint16_t* __restrict__ ybf) {
    __shared__ uint16_t P[4][16 * 72];               // per-wave P tile, pitch 72
    int blk = blockIdx.x;
    int qb = blk & 15, h = (blk >> 4) & 7, e = (blk >> 7) & 1, b = blk >> 8;
    int tid = threadIdx.x, lane = tid & 63, w = tid >> 6;
    int qw = qb * 64 + w * 16;
    const uint16_t* Qb = Qh + ((size_t)((b * 2 + e) * 8 + h) * 1024 + qw) * 64;
    const uint16_t* Kb = Kh + (size_t)(b * 8 + h) * 1024 * 64;
    const uint16_t* Vb = Vt + (size_t)(b * 8 + h) * 64 * 1024;
    uint16_t* P_w = P[w];
    int cl = lane & 15, gp = lane >> 4;
    bf16x8 qf[2];
    qf[0] = *(const bf16x8*)&Qb[cl * 64 + gp * 8];
    qf[1] = *(const bf16x8*)&Qb[cl * 64 + 32 + gp * 8];
    f32x4 o[4];
    float m[4], ls[4];
#pragma unroll
    for (int t = 0; t < 4; t++)
#pragma unroll
        for (int r = 0; r < 4; r++) o[t][r] = 0.f;
#pragma unroll
    for (int r = 0; r < 4; r++) { m[r] = -INFINITY; ls[r] = 0.f; }

    for (int jt = 0; jt <= qw + 15; jt += 64) {
        f32x4 s[4];
#pragma unroll
        for (int t = 0; t < 4; t++)
#pragma unroll
            for (int r = 0; r < 4; r++) s[t][r] = 0.f;
#pragma unroll
        for (int kf = 0; kf < 2; kf++) {
#pragma unroll
            for (int t = 0; t < 4; t++) {
                bf16x8 kfr = *(const bf16x8*)&Kb[(size_t)(jt + t * 16 + cl) * 64 + kf * 32 + gp * 8];
                s[t] = mfma16(qf[kf], kfr, s[t]);
            }
        }
        // scale + causal mask
#pragma unroll
        for (int t = 0; t < 4; t++) {
            int kvc = jt + t * 16 + cl;
#pragma unroll
            for (int r = 0; r < 4; r++) {
                float v = s[t][r] * 0.125f;
                int qg = qw + gp * 4 + r;
                s[t][r] = (kvc <= qg) ? v : -INFINITY;
            }
        }
        // online softmax per row (rows live in 16-lane groups; reduce over lane&15)
#pragma unroll
        for (int r = 0; r < 4; r++) {
            float v = fmaxf(fmaxf(s[0][r], s[1][r]), fmaxf(s[2][r], s[3][r]));
            for (int xm = 1; xm < 16; xm <<= 1) v = fmaxf(v, __shfl_xor(v, xm));
            float mn = fmaxf(m[r], v);
            float sc = __expf(m[r] - mn);
            m[r] = mn;
            float lsum = 0.f;
#pragma unroll
            for (int t = 0; t < 4; t++) {
                float p = __expf(s[t][r] - mn);
                s[t][r] = p;
                lsum += p;
            }
            for (int xm = 1; xm < 16; xm <<= 1) lsum += __shfl_xor(lsum, xm);
            ls[r] = ls[r] * sc + lsum;
#pragma unroll
            for (int t = 0; t < 4; t++) o[t][r] *= sc;
        }
        // P -> per-wave LDS (transpose D-layout -> A-layout)
#pragma unroll
        for (int t = 0; t < 4; t++)
#pragma unroll
            for (int r = 0; r < 4; r++)
                P_w[(gp * 4 + r) * 72 + t * 16 + cl] = f2bf(s[t][r]);
        // PV
#pragma unroll
        for (int kf = 0; kf < 2; kf++) {
            bf16x8 pa = *(const bf16x8*)&P_w[cl * 72 + kf * 32 + gp * 8];
#pragma unroll
            for (int t = 0; t < 4; t++) {
                bf16x8 vf = *(const bf16x8*)&Vb[(size_t)(t * 16 + cl) * 1024 + jt + kf * 32 + gp * 8];
                o[t] = mfma16(pa, vf, o[t]);
            }
        }
    }
    uint16_t* yb = ybf + ((size_t)(b * 2 + e) * 1024 + qw) * 512 + h * 64;
#pragma unroll
    for (int r = 0; r < 4; r++) {
        float inv = 1.f / ls[r];
#pragma unroll
        for (int t = 0; t < 4; t++)
            yb[(size_t)(gp * 4 + r) * 512 + t * 16 + cl] = f2bf(o[t][r] * inv);
    }
}

// 9. copy x -> out
__global__ void k_copy(const float4* __restrict__ src, float4* __restrict__ dst, int n4) {
    int i = blockIdx.x * blockDim.x + threadIdx.x;
    if (i < n4) dst[i] = src[i];
}

// 10. gated combine + scatter-add into out
__global__ void k_combine(const float* __restrict__ yproj, const int* __restrict__ idx,
                          const float* __restrict__ wsel, const float* __restrict__ gate,
                          float* __restrict__ out) {
    int blk = blockIdx.x; int b = blk >> 10, i = blk & 1023;
    int tid = threadIdx.x;   // 128
    int t = idx[blk];
    float wv = wsel[blk], g0 = gate[blk * 2], g1 = gate[blk * 2 + 1];
    const float4* y0 = (const float4*)(yproj + ((size_t)(b * 2 + 0) * 1024 + i) * 512);
    const float4* y1 = (const float4*)(yproj + ((size_t)(b * 2 + 1) * 1024 + i) * 512);
    float4* ob = (float4*)(out + ((size_t)b * 2048 + t) * 512);
    float4 a = y0[tid], c = y1[tid], o = ob[tid];
    o.x += wv * (g0 * a.x + g1 * c.x);
    o.y += wv * (g0 * a.y + g1 * c.y);
    o.z += wv * (g0 * a.z + g1 * c.z);
    o.w += wv * (g0 * a.w + g1 * c.w);
    ob[tid] = o;
}

// 11. BCE loss partials (wave per token row)
__global__ void k_loss(const float* __restrict__ x, const float* __restrict__ wp,
                       const int* __restrict__ mask, float* __restrict__ lossp) {
    __shared__ float red[4];
    int wl = threadIdx.x >> 6, lane = threadIdx.x & 63;
    int row = blockIdx.x * 4 + wl;
    const float* xr = x + (size_t)row * 512;
    float s = 0.f;
#pragma unroll
    for (int j = 0; j < 8; j++) { int c = lane + 64 * j; s += xr[c] * wp[c]; }
    for (int m = 1; m < 64; m <<= 1) s += __shfl_xor(s, m);
    if (lane == 0) {
        float pl = s;
        float tgt = (float)mask[row];
        red[wl] = fmaxf(pl, 0.f) - pl * tgt + log1pf(__expf(-fabsf(pl)));
    }
    __syncthreads();
    if (threadIdx.x == 0) lossp[blockIdx.x] = red[0] + red[1] + red[2] + red[3];
}

__global__ void k_loss_final(const float* __restrict__ lossp, float* __restrict__ outloss) {
    __shared__ float red[16];
    int tid = threadIdx.x;   // 1024
    float v = lossp[tid];
    for (int m = 1; m < 64; m <<= 1) v += __shfl_xor(v, m);
    int lane = tid & 63, w = tid >> 6;
    if (lane == 0) red[w] = v;
    __syncthreads();
    if (tid == 0) {
        float s = 0.f;
        for (int q = 0; q < 16; q++) s += red[q];
        outloss[0] = s * (1.0f / 4096.0f);
    }
}

// ---------------------------------------------------------------------------
extern "C" void kernel_launch(void* const* d_in, const int* in_sizes, int n_in,
                              void* d_out, int out_size, void* d_ws, size_t ws_size,
                              hipStream_t stream) {
    const float* x        = (const float*)d_in[0];
    const float* W_router = (const float*)d_in[1];
    const float* W_q      = (const float*)d_in[2];
    const float* W_kv     = (const float*)d_in[3];
    const float* W_proj   = (const float*)d_in[4];
    const float* ln_w     = (const float*)d_in[5];
    const float* W_gate   = (const float*)d_in[6];
    const float* W_pred   = (const float*)d_in[7];
    // d_in[8] = k (device scalar); fixed at 1024 for this problem.

    char* ws = (char*)d_ws;
    float*    logits = (float*)   (ws + OFF_LOGITS);
    int*      mask   = (int*)     (ws + OFF_MASK);
    int*      idx    = (int*)     (ws + OFF_IDX);
    float*    wsel   = (float*)   (ws + OFF_WSEL);
    float*    gate   = (float*)   (ws + OFF_GATE);
    float*    lossp  = (float*)   (ws + OFF_LOSSP);
    uint16_t* selbf  = (uint16_t*)(ws + OFF_SELBF);
    uint16_t* Wqkvt  = (uint16_t*)(ws + OFF_WQKVT);
    uint16_t* Wprojt = (uint16_t*)(ws + OFF_WPROJT);
    float*    qkvraw = (float*)   (ws + OFF_QKVRAW);
    uint16_t* Qh     = (uint16_t*)(ws + OFF_QH);
    uint16_t* Kh     = (uint16_t*)(ws + OFF_KH);
    uint16_t* Vt     = (uint16_t*)(ws + OFF_VT);
    uint16_t* ybf    = (uint16_t*)(ws + OFF_YBF);
    float*    yproj  = (float*)   (ws + OFF_YPROJ);
    float*    out    = (float*)d_out;

    k_logits     <<<1024, 256, 0, stream>>>(x, W_router, logits);
    k_rank       <<<1024, 256, 0, stream>>>(logits, mask);
    k_select     <<<2, 1024, 0, stream>>>(logits, mask, idx, wsel);
    k_castw      <<<5120, 256, 0, stream>>>(W_q, W_kv, W_proj, Wqkvt, Wprojt);
    k_gather_gate<<<2048, 256, 0, stream>>>(x, idx, W_gate, selbf, gate);
    k_gemm       <<<dim3(16, 16), 256, 0, stream>>>(selbf, Wqkvt, qkvraw, 2048, 2048, 512);
    k_norm_rope  <<<2048, 256, 0, stream>>>(qkvraw, ln_w, Qh, Kh, Vt);
    k_attn       <<<512, 256, 0, stream>>>(Qh, Kh, Vt, ybf);
    k_gemm       <<<dim3(32, 4), 256, 0, stream>>>(ybf, Wprojt, yproj, 4096, 512, 512);
    k_copy       <<<2048, 256, 0, stream>>>((const float4*)x, (float4*)out, 524288);
    k_combine    <<<2048, 128, 0, stream>>>(yproj, idx, wsel, gate, out);
    k_loss       <<<1024, 256, 0, stream>>>(x, W_pred, mask, lossp);
    k_loss_final <<<1, 1024, 0, stream>>>(lossp, out + 2097152);
}